// Round 2
// baseline (341.890 us; speedup 1.0000x reference)
//
#include <hip/hip_runtime.h>

// QLoRA NF4 forward: out[b,s,o] = 4.0 * sum_r (sum_i x[b,s,i]*W_A[r,i]) * W_B[o,r]
// B=4 S=2048 IN=4096 OUT=4096 R=8. All fp32.
// R2: split-K phase 1 — each wave owns IN/4 for ALL 8 rows, so wA is read
// exactly once per block (was 4x). VMEM instrs/block: 57K -> 33K.

static __device__ __constant__ float NF4_TBL[16] = {
    -1.0f, -0.6961928009986877f, -0.5250730514526367f, -0.39491748809814453f,
    -0.28444138169288635f, -0.18477343022823334f, -0.09105003625154495f, 0.0f,
    0.07958029955625534f, 0.16093020141124725f, 0.24611230194568634f,
    0.33791524171829224f, 0.44070982933044434f, 0.5626170039176941f,
    0.7229568362236328f, 1.0f};

__global__ void nf4_dequant_kernel(const int* __restrict__ codesA,
                                   const float* __restrict__ absA,
                                   const int* __restrict__ codesB,
                                   const float* __restrict__ absB,
                                   float* __restrict__ wA,
                                   float* __restrict__ wB,
                                   int n) {
    int id = blockIdx.x * blockDim.x + threadIdx.x;
    if (id < n) {
        wA[id] = NF4_TBL[codesA[id] & 15] * absA[id >> 6];
        wB[id] = NF4_TBL[codesB[id] & 15] * absB[id >> 6];
    }
}

// Block = 8 rows of x, 256 threads (4 waves).
// Phase 1 (split-K): wave w handles float4-columns [256w, 256w+256) of all
//   8 rows; 64 accumulators/thread; butterfly shfl_xor reduce (lane ends
//   owning sum for (row=lane>>3, r=lane&7)); LDS combine across 4 waves.
// Phase 2: each thread emits 16 float4 of out per k-slice, wB rows
//   register-cached across the 8-row loop.
__global__ __launch_bounds__(256, 4) void qlora_fused_kernel(
    const float* __restrict__ x,     // [8192, 4096]
    const float* __restrict__ wA,    // [8, 4096]
    const float* __restrict__ wB,    // [4096, 8]
    float* __restrict__ out) {       // [8192, 4096]
    constexpr int IN4  = 4096 / 4;   // float4 per row
    constexpr int ROWS = 8;

    __shared__ float  partial[4][64];
    __shared__ float4 interm4[ROWS][2];    // interm[8][8], 16B-aligned

    const int t    = threadIdx.x;
    const int wave = t >> 6;
    const int lane = t & 63;
    const int row0 = blockIdx.x * ROWS;

    // ---- Phase 1 ----
    {
        const float4* __restrict__ x4  = (const float4*)x + (size_t)row0 * IN4;
        const float4* __restrict__ wA4 = (const float4*)wA;
        const int colbase = wave * 256;

        float acc[64];
        #pragma unroll
        for (int i = 0; i < 64; ++i) acc[i] = 0.f;

        #pragma unroll
        for (int c = 0; c < 4; ++c) {
            const int idx = colbase + 64 * c + lane;   // coalesced per wave
            float4 w[8];
            #pragma unroll
            for (int r = 0; r < 8; ++r) w[r] = wA4[r * IN4 + idx];
            #pragma unroll
            for (int row = 0; row < ROWS; ++row) {
                const float4 xa = x4[row * IN4 + idx];
                #pragma unroll
                for (int r = 0; r < 8; ++r)
                    acc[row * 8 + r] += xa.x * w[r].x + xa.y * w[r].y
                                      + xa.z * w[r].z + xa.w * w[r].w;
            }
        }

        // Value-halving butterfly: 64 values over 64 lanes -> lane owns sum
        // for index i == lane. 63 shuffles/thread, all reg indices static.
        #pragma unroll
        for (int s = 0; s < 6; ++s) {
            const int d  = 1 << s;
            const int cnt = 32 >> s;                   // values after stage
            const bool kb = (lane & d) != 0;
            #pragma unroll
            for (int j = 0; j < 32; ++j) {             // guard keeps it static
                if (j < cnt) {
                    const float a0 = acc[2 * j];
                    const float a1 = acc[2 * j + 1];
                    const float keep = kb ? a1 : a0;
                    const float send = kb ? a0 : a1;
                    acc[j] = keep + __shfl_xor(send, d, 64);
                }
            }
        }
        partial[wave][lane] = acc[0];
    }
    __syncthreads();
    if (wave == 0) {
        const float s = partial[0][lane] + partial[1][lane]
                      + partial[2][lane] + partial[3][lane];
        ((float*)interm4)[lane] = s * 4.0f;            // SCALING folded in
    }
    __syncthreads();

    // ---- Phase 2: out[row0+m][o] = sum_r interm[m][r] * W_B[o][r] ----
    const float4* __restrict__ wB4 = (const float4*)wB;
    #pragma unroll
    for (int k = 0; k < 4; ++k) {
        const int og = t + 256 * k;                    // float4 group in row
        float4 wrow[8];
        #pragma unroll
        for (int j = 0; j < 8; ++j) wrow[j] = wB4[8 * og + j];

        #pragma unroll
        for (int m = 0; m < ROWS; ++m) {
            const float4 i0 = interm4[m][0];
            const float4 i1 = interm4[m][1];
            float4 s;
            s.x = i0.x * wrow[0].x + i0.y * wrow[0].y + i0.z * wrow[0].z + i0.w * wrow[0].w
                + i1.x * wrow[1].x + i1.y * wrow[1].y + i1.z * wrow[1].z + i1.w * wrow[1].w;
            s.y = i0.x * wrow[2].x + i0.y * wrow[2].y + i0.z * wrow[2].z + i0.w * wrow[2].w
                + i1.x * wrow[3].x + i1.y * wrow[3].y + i1.z * wrow[3].z + i1.w * wrow[3].w;
            s.z = i0.x * wrow[4].x + i0.y * wrow[4].y + i0.z * wrow[4].z + i0.w * wrow[4].w
                + i1.x * wrow[5].x + i1.y * wrow[5].y + i1.z * wrow[5].z + i1.w * wrow[5].w;
            s.w = i0.x * wrow[6].x + i0.y * wrow[6].y + i0.z * wrow[6].z + i0.w * wrow[6].w
                + i1.x * wrow[7].x + i1.y * wrow[7].y + i1.z * wrow[7].z + i1.w * wrow[7].w;
            ((float4*)(out + (size_t)(row0 + m) * 4096))[og] = s;
        }
    }
}

extern "C" void kernel_launch(void* const* d_in, const int* in_sizes, int n_in,
                              void* d_out, int out_size, void* d_ws, size_t ws_size,
                              hipStream_t stream) {
    const float* x        = (const float*)d_in[0];
    const int*   codes_A  = (const int*)d_in[1];
    const float* absmax_A = (const float*)d_in[2];
    const int*   codes_B  = (const int*)d_in[3];
    const float* absmax_B = (const float*)d_in[4];
    float* out = (float*)d_out;

    constexpr int NW = 8 * 4096;
    float* wA = (float*)d_ws;
    float* wB = (float*)d_ws + NW;

    nf4_dequant_kernel<<<(NW + 255) / 256, 256, 0, stream>>>(
        codes_A, absmax_A, codes_B, absmax_B, wA, wB, NW);

    const int n_rows = 4 * 2048;
    qlora_fused_kernel<<<n_rows / 8, 256, 0, stream>>>(x, wA, wB, out);
}

// Round 3
// 257.616 us; speedup vs baseline: 1.3271x; 1.3271x over previous
//
#include <hip/hip_runtime.h>

// QLoRA NF4 forward: out[b,s,o] = 4.0 * sum_r (sum_i x[b,s,i]*W_A[r,i]) * W_B[o,r]
// B=4 S=2048 IN=4096 OUT=4096 R=8. All fp32.
// R3: three kernels, pure streams.
//  - dequant writes wA [8][4096] and wB TRANSPOSED wBt [8][4096] (kills the
//    128B-stride gather that serialized R1's phase 2).
//  - K1 (lora_a): x -> interm [8192][8], read-only stream, R1's proven
//    no-spill register budget (acc[16]).
//  - K2 (lora_b): interm @ wBt -> out, write-only stream, 2048 blocks for
//    full occupancy, interm via wave-uniform (scalar) loads.

static __device__ __constant__ float NF4_TBL[16] = {
    -1.0f, -0.6961928009986877f, -0.5250730514526367f, -0.39491748809814453f,
    -0.28444138169288635f, -0.18477343022823334f, -0.09105003625154495f, 0.0f,
    0.07958029955625534f, 0.16093020141124725f, 0.24611230194568634f,
    0.33791524171829224f, 0.44070982933044434f, 0.5626170039176941f,
    0.7229568362236328f, 1.0f};

__global__ void nf4_dequant_kernel(const int* __restrict__ codesA,
                                   const float* __restrict__ absA,
                                   const int* __restrict__ codesB,
                                   const float* __restrict__ absB,
                                   float* __restrict__ wA,    // [8][4096]
                                   float* __restrict__ wBt,   // [8][4096] (transposed)
                                   int n) {
    int id = blockIdx.x * blockDim.x + threadIdx.x;
    if (id < n) {
        wA[id] = NF4_TBL[codesA[id] & 15] * absA[id >> 6];
        // codes_B flat id = o*8 + r ; store transposed at [r][o]
        const int o = id >> 3;
        const int r = id & 7;
        wBt[r * 4096 + o] = NF4_TBL[codesB[id] & 15] * absB[id >> 6];
    }
}

// K1: interm[row][r] = 4.0 * sum_i x[row][i] * wA[r][i]
// Block = 8 rows (4 waves, wave owns 2 rows). 1024 blocks.
__global__ __launch_bounds__(256, 4) void lora_a_kernel(
    const float* __restrict__ x,       // [8192][4096]
    const float* __restrict__ wA,      // [8][4096]
    float* __restrict__ interm) {      // [8192][8]
    constexpr int IN4 = 4096 / 4;

    const int t    = threadIdx.x;
    const int wave = t >> 6;
    const int lane = t & 63;
    const int r0   = blockIdx.x * 8 + 2 * wave;   // this wave's first row

    const float4* __restrict__ x0  = (const float4*)(x + (size_t)r0 * 4096);
    const float4* __restrict__ x1  = (const float4*)(x + (size_t)(r0 + 1) * 4096);
    const float4* __restrict__ wA4 = (const float4*)wA;

    float acc0[8], acc1[8];
    #pragma unroll
    for (int r = 0; r < 8; ++r) { acc0[r] = 0.f; acc1[r] = 0.f; }

    #pragma unroll 4
    for (int c = 0; c < 16; ++c) {
        const int idx = lane + 64 * c;            // coalesced per wave
        const float4 xa = x0[idx];
        const float4 xb = x1[idx];
        #pragma unroll
        for (int r = 0; r < 8; ++r) {
            const float4 w = wA4[r * IN4 + idx];  // coalesced, L2-resident
            acc0[r] += xa.x * w.x + xa.y * w.y + xa.z * w.z + xa.w * w.w;
            acc1[r] += xb.x * w.x + xb.y * w.y + xb.z * w.z + xb.w * w.w;
        }
    }

    #pragma unroll
    for (int r = 0; r < 8; ++r) {
        float v0 = acc0[r], v1 = acc1[r];
        #pragma unroll
        for (int off = 32; off > 0; off >>= 1) {
            v0 += __shfl_down(v0, off, 64);
            v1 += __shfl_down(v1, off, 64);
        }
        if (lane == 0) {
            interm[(size_t)r0 * 8 + r]       = v0 * 4.0f;   // SCALING folded
            interm[(size_t)(r0 + 1) * 8 + r] = v1 * 4.0f;
        }
    }
}

// K2: out[row][o] = sum_r interm[row][r] * wBt[r][o]
// Block = 4 rows, 2048 blocks (8 blocks/CU -> 100% occupancy).
// interm rows are block-uniform -> scalar loads; wBt reads lane-contiguous.
__global__ __launch_bounds__(256, 8) void lora_b_kernel(
    const float* __restrict__ interm,  // [8192][8]
    const float* __restrict__ wBt,     // [8][4096]
    float* __restrict__ out) {         // [8192][4096]
    const int t    = threadIdx.x;
    const int row0 = blockIdx.x * 4;

    float im[4][8];
    const float* __restrict__ ip = interm + (size_t)row0 * 8;  // uniform address
    #pragma unroll
    for (int m = 0; m < 4; ++m)
        #pragma unroll
        for (int r = 0; r < 8; ++r)
            im[m][r] = ip[m * 8 + r];                          // scalarizes

    const float4* __restrict__ wt = (const float4*)wBt;        // [8][1024]

    #pragma unroll
    for (int k = 0; k < 4; ++k) {
        const int og = t + 256 * k;                            // float4 col group
        float4 w[8];
        #pragma unroll
        for (int r = 0; r < 8; ++r) w[r] = wt[r * 1024 + og];  // coalesced

        #pragma unroll
        for (int m = 0; m < 4; ++m) {
            float4 s;
            s.x = im[m][0] * w[0].x + im[m][1] * w[1].x + im[m][2] * w[2].x
                + im[m][3] * w[3].x + im[m][4] * w[4].x + im[m][5] * w[5].x
                + im[m][6] * w[6].x + im[m][7] * w[7].x;
            s.y = im[m][0] * w[0].y + im[m][1] * w[1].y + im[m][2] * w[2].y
                + im[m][3] * w[3].y + im[m][4] * w[4].y + im[m][5] * w[5].y
                + im[m][6] * w[6].y + im[m][7] * w[7].y;
            s.z = im[m][0] * w[0].z + im[m][1] * w[1].z + im[m][2] * w[2].z
                + im[m][3] * w[3].z + im[m][4] * w[4].z + im[m][5] * w[5].z
                + im[m][6] * w[6].z + im[m][7] * w[7].z;
            s.w = im[m][0] * w[0].w + im[m][1] * w[1].w + im[m][2] * w[2].w
                + im[m][3] * w[3].w + im[m][4] * w[4].w + im[m][5] * w[5].w
                + im[m][6] * w[6].w + im[m][7] * w[7].w;
            ((float4*)(out + (size_t)(row0 + m) * 4096))[og] = s;  // coalesced
        }
    }
}

extern "C" void kernel_launch(void* const* d_in, const int* in_sizes, int n_in,
                              void* d_out, int out_size, void* d_ws, size_t ws_size,
                              hipStream_t stream) {
    const float* x        = (const float*)d_in[0];
    const int*   codes_A  = (const int*)d_in[1];
    const float* absmax_A = (const float*)d_in[2];
    const int*   codes_B  = (const int*)d_in[3];
    const float* absmax_B = (const float*)d_in[4];
    float* out = (float*)d_out;

    constexpr int NW = 8 * 4096;                 // elements per factor
    float* wA     = (float*)d_ws;                // 128 KB
    float* wBt    = (float*)d_ws + NW;           // 128 KB (transposed)
    float* interm = (float*)d_ws + 2 * NW;       // 8192*8 fp32 = 256 KB

    nf4_dequant_kernel<<<(NW + 255) / 256, 256, 0, stream>>>(
        codes_A, absmax_A, codes_B, absmax_B, wA, wBt, NW);

    lora_a_kernel<<<8192 / 8, 256, 0, stream>>>(x, wA, interm);
    lora_b_kernel<<<8192 / 4, 256, 0, stream>>>(interm, wBt, out);
}